// Round 9
// baseline (533.187 us; speedup 1.0000x reference)
//
#include <hip/hip_runtime.h>
#include <hip/hip_cooperative_groups.h>

namespace cg = cooperative_groups;

// Problem constants (fixed by the reference file).
static constexpr int B  = 16;
static constexpr int N  = 250000;   // 15625 * 16
static constexpr int F  = 500000;
static constexpr int C3 = 3 * F;    // corners = 1,500,000
static constexpr int RW = 48;       // ushorts per vt row: 3 comps * 16 batches (96 B)
static constexpr int CAP = 32;      // pairs/vertex; Poisson(6), overflow P ~ 2e-8
static constexpr int NT  = N / 16;        // transpose tiles = 15625
static constexpr int NGT = (N + 63) / 64; // gather tiles   = 3907

// ---- workspace layout (bytes): vt | deg (unpadded) | adjp[N][CAP] ----
static constexpr size_t D_VT   = 0;                              // 24,000,000
static constexpr size_t D_DEG  = (size_t)N * RW * 2;             // 24,000,000
static constexpr size_t D_ADJ  = D_DEG + (size_t)N * 4;          // 25,000,000
static constexpr size_t D_NEED = D_ADJ + (size_t)N * CAP * 8;    // 89,000,000 (R7-proven fit)

// Cooperative grid: 6 blocks/CU x 256 CUs. __launch_bounds__(256,6) caps VGPR<=85
// so all G blocks are co-resident (grid.sync deadlock-safe; API validates too).
static constexpr int G  = 1536;
static constexpr int GT = 512;   // blocks [0,GT) transpose; [GT,G) do corners

__device__ __forceinline__ unsigned short f2bf(float f) {
    unsigned u = __float_as_uint(f);
    return (unsigned short)((u + 0x7FFFu + ((u >> 16) & 1u)) >> 16);  // RNE
}

// ---------------- shared device helpers ----------------

__device__ __forceinline__ void transpose_tile(int tile, int t,
    const float* __restrict__ vert, unsigned short* __restrict__ vt,
    unsigned short* lus)
{
    int n0 = tile * 16;
    int b = t >> 4, v = t & 15;
    const float* s = vert + (size_t)b * (N * 3) + (size_t)(n0 + v) * 3;  // coalesced
    lus[v * RW + 0 * 16 + b] = f2bf(s[0]);
    lus[v * RW + 1 * 16 + b] = f2bf(s[1]);
    lus[v * RW + 2 * 16 + b] = f2bf(s[2]);
    __syncthreads();
    const uint2* lu2 = (const uint2*)lus;
    uint2* d2 = (uint2*)(vt + (size_t)n0 * RW);
    if (t < 192) d2[t] = lu2[t];             // coalesced 1536 B per tile
}

__device__ __forceinline__ void corner_decode(int e, const int* __restrict__ faces,
                                              int& dst, long long& pack)
{
    int f = e / 3;
    int c = e - 3 * f;
    int a  = faces[3 * f + 0];
    int b  = faces[3 * f + 1];
    int cc = faces[3 * f + 2];
    dst    = (c == 0) ? a : (c == 1) ? b : cc;
    int p0 = (c == 0) ? b : a;
    int p1 = (c == 2) ? b : cc;
    pack = (long long)(((unsigned long long)(unsigned)p0) |
                       ((unsigned long long)(unsigned)p1 << 32));
}

// 4 lanes per vertex; lane q owns batches 4q..4q+3 via uint2 (8 B) loads.
__device__ __forceinline__ void acc_row(const unsigned short* __restrict__ r,
                                        int q, float (&acc)[3][4]) {
#pragma unroll
    for (int cc = 0; cc < 3; ++cc) {
        uint2 u = *(const uint2*)(r + cc * 16 + 4 * q);
        acc[cc][0] += __uint_as_float(u.x << 16);
        acc[cc][1] += __uint_as_float(u.x & 0xFFFF0000u);
        acc[cc][2] += __uint_as_float(u.y << 16);
        acc[cc][3] += __uint_as_float(u.y & 0xFFFF0000u);
    }
}

__device__ __forceinline__ void gather_tile(int tile, int t,
    const unsigned short* __restrict__ vt, const int* __restrict__ adj,
    const unsigned* __restrict__ deg, float* __restrict__ out, float* lds)
{
    int q = t & 3;
    int v = t >> 2;
    int n = tile * 64 + v;
    bool n_ok = (n < N);

    unsigned d = n_ok ? deg[n] : 0u;
    if (d > 2u * CAP) d = 2u * CAP;
    const int* a0 = adj + (size_t)n * (CAP * 2);

    float acc[3][4] = {{0,0,0,0},{0,0,0,0},{0,0,0,0}};
    unsigned j = 0;
    for (; j + 4 <= d; j += 4) {
        int2 p0 = *(const int2*)(a0 + j);
        int2 p1 = *(const int2*)(a0 + j + 2);
        acc_row(vt + (size_t)p0.x * RW, q, acc);
        acc_row(vt + (size_t)p0.y * RW, q, acc);
        acc_row(vt + (size_t)p1.x * RW, q, acc);
        acc_row(vt + (size_t)p1.y * RW, q, acc);
    }
    if (j < d) {                              // deg even: remainder exactly 0 or 2
        int2 p0 = *(const int2*)(a0 + j);
        acc_row(vt + (size_t)p0.x * RW, q, acc);
        acc_row(vt + (size_t)p0.y * RW, q, acc);
    }

    if (n_ok) {
        float self[3][4];
        const unsigned short* rs = vt + (size_t)n * RW;
#pragma unroll
        for (int cc = 0; cc < 3; ++cc) {
            uint2 u = *(const uint2*)(rs + cc * 16 + 4 * q);
            self[cc][0] = __uint_as_float(u.x << 16);
            self[cc][1] = __uint_as_float(u.x & 0xFFFF0000u);
            self[cc][2] = __uint_as_float(u.y << 16);
            self[cc][3] = __uint_as_float(u.y & 0xFFFF0000u);
        }
        float inv = 1.0f / fmaxf((float)d, 1.0f);
#pragma unroll
        for (int k = 0; k < 4; ++k) {
            float lx = acc[0][k] * inv - self[0][k];
            float ly = acc[1][k] * inv - self[1][k];
            float lz = acc[2][k] * inv - self[2][k];
            lds[(4 * q + k) * 65 + v] = sqrtf(lx * lx + ly * ly + lz * lz);
        }
    }
    __syncthreads();
    int vo = t & 63;
    int nn = tile * 64 + vo;
    if (nn < N) {
#pragma unroll
        for (int k = 0; k < 4; ++k) {
            int bo = (t >> 6) + 4 * k;
            out[(size_t)bo * N + nn] = lds[bo * 65 + vo];   // coalesced
        }
    }
}

// ---------------- cooperative mono-kernel ----------------

__global__ __launch_bounds__(256, 6) void uls_mono(
    const float* __restrict__ vert, const int* __restrict__ faces,
    unsigned short* __restrict__ vt, unsigned* __restrict__ deg,
    long long* __restrict__ adjp, float* __restrict__ out)
{
    cg::grid_group grid = cg::this_grid();
    __shared__ float lds_f[16 * 65];          // 4160 B: gather layout; aliased by transpose
    int t   = threadIdx.x;
    int blk = blockIdx.x;

    // Phase Z: zero deg (ws is poisoned 0xAA each call)
    for (int i = blk * 256 + t; i < N; i += G * 256) deg[i] = 0u;
    grid.sync();

    // Phase A: block-role split — streaming transpose || latency-bound corners.
    // Co-resident on the same CUs, the two overlap ~max not sum (m114).
    if (blk < GT) {
        unsigned short* lus = (unsigned short*)lds_f;
        for (int tile = blk; tile < NT; tile += GT) {
            __syncthreads();                  // protect LDS reuse across iterations
            transpose_tile(tile, t, vert, vt, lus);
        }
    } else {
        const int str = (G - GT) * 256;
        int e = (blk - GT) * 256 + t;
        // 2-deep pipeline: two independent atomics in flight before their stores
        for (; e + str < C3; e += 2 * str) {
            int dA, dB; long long pkA, pkB;
            corner_decode(e,       faces, dA, pkA);
            corner_decode(e + str, faces, dB, pkB);
            unsigned rA = atomicAdd(&deg[dA], 2u);
            unsigned rB = atomicAdd(&deg[dB], 2u);
            unsigned piA = rA >> 1;
            unsigned piB = rB >> 1;
            if (piA < (unsigned)CAP) adjp[(size_t)dA * CAP + piA] = pkA;
            if (piB < (unsigned)CAP) adjp[(size_t)dB * CAP + piB] = pkB;
        }
        if (e < C3) {
            int dA; long long pkA;
            corner_decode(e, faces, dA, pkA);
            unsigned rA = atomicAdd(&deg[dA], 2u);
            unsigned piA = rA >> 1;
            if (piA < (unsigned)CAP) adjp[(size_t)dA * CAP + piA] = pkA;
        }
    }
    grid.sync();

    // Phase B: gather
    for (int tile = blk; tile < NGT; tile += G) {
        __syncthreads();                      // protect LDS reuse across iterations
        gather_tile(tile, t, vt, (const int*)adjp, deg, out, lds_f);
    }
}

// ---------------- classic fallback (R8-proven structure, shared helpers) ----------------

__global__ __launch_bounds__(256) void k_transpose(
    const float* __restrict__ vert, unsigned short* __restrict__ vt)
{
    __shared__ unsigned short lus[16 * RW];
    transpose_tile(blockIdx.x, threadIdx.x, vert, vt, lus);
}

__global__ __launch_bounds__(256) void k_corner(
    const int* __restrict__ faces, unsigned* __restrict__ deg,
    long long* __restrict__ adjp)
{
    int e = blockIdx.x * 256 + threadIdx.x;
    if (e >= C3) return;
    int dA; long long pkA;
    corner_decode(e, faces, dA, pkA);
    unsigned rA = atomicAdd(&deg[dA], 2u);
    unsigned piA = rA >> 1;
    if (piA < (unsigned)CAP) adjp[(size_t)dA * CAP + piA] = pkA;
}

__global__ __launch_bounds__(256) void k_gather(
    const unsigned short* __restrict__ vt, const int* __restrict__ adj,
    const unsigned* __restrict__ deg, float* __restrict__ out)
{
    __shared__ float lds_f[16 * 65];
    gather_tile(blockIdx.x, threadIdx.x, vt, adj, deg, out, lds_f);
}

// ---------------- launcher ----------------

extern "C" void kernel_launch(void* const* d_in, const int* in_sizes, int n_in,
                              void* d_out, int out_size, void* d_ws, size_t ws_size,
                              hipStream_t stream) {
    const float* vert  = (const float*)d_in[0];   // (B, N, 3) fp32
    const int*   faces = (const int*)d_in[1];     // (F, 3) int32
    float* out = (float*)d_out;                   // (B, N) fp32
    char* ws = (char*)d_ws;
    (void)ws_size;  // D_NEED = 89 MB, proven to fit in R7

    unsigned short* vt   = (unsigned short*)(ws + D_VT);
    unsigned*       deg  = (unsigned*)(ws + D_DEG);
    long long*      adjp = (long long*)(ws + D_ADJ);

    {
        void* args[] = { (void*)&vert, (void*)&faces, (void*)&vt,
                         (void*)&deg, (void*)&adjp, (void*)&out };
        hipError_t err = hipLaunchCooperativeKernel((const void*)uls_mono,
                                                    dim3(G), dim3(256),
                                                    args, 0, stream);
        if (err == hipSuccess) return;
        (void)hipGetLastError();              // clear; fall back to classic path
    }

    // Classic 4-dispatch fallback (proven ~265 us)
    hipMemsetAsync(deg, 0, (size_t)N * sizeof(unsigned), stream);
    k_transpose<<<NT, 256, 0, stream>>>(vert, vt);
    k_corner<<<(C3 + 255) / 256, 256, 0, stream>>>(faces, deg, adjp);
    k_gather<<<NGT, 256, 0, stream>>>(vt, (const int*)adjp, deg, out);
}